// Round 1
// baseline (2794.291 us; speedup 1.0000x reference)
//
#include <hip/hip_runtime.h>

#define NN 50000      // nodes
#define RR 47         // relations
#define ED 1600       // emb dim
#define WS 16         // weights size (layer1 out)
#define NC 50         // classes
#define NB 40         // bases
#define NE 1600000    // edges
#define WJ (RR*WS)    // 752 = layer1 fused output width

// ---------------- counting: cnt[col] += 1 ----------------
__global__ void count_kernel(const int* __restrict__ cols, float* __restrict__ cnt) {
    int e = blockIdx.x * blockDim.x + threadIdx.x;
    if (e < NE) atomicAdd(&cnt[cols[e]], 1.0f);
}

// ---------------- Wbig[i][r*16+o] = sum_b comps1[r,b]*bases1[b,i,o] ----------------
__global__ void wbig_kernel(const float* __restrict__ comps1, const float* __restrict__ bases1,
                            float* __restrict__ Wbig) {
    int idx = blockIdx.x * blockDim.x + threadIdx.x;   // i*WJ + j,  j = r*16+o
    if (idx >= ED * WJ) return;
    int i = idx / WJ;
    int j = idx - i * WJ;
    int r = j >> 4;
    int o = j & 15;
    float s = 0.f;
#pragma unroll
    for (int b = 0; b < NB; ++b)
        s += comps1[r * NB + b] * bases1[(b * ED + i) * WS + o];
    Wbig[idx] = s;
}

// ---------------- fp32 tiled GEMM: C[M,N] = A[M,K] @ B[K,N] ----------------
#define BM 64
#define BN 64
#define BK 16
__global__ __launch_bounds__(256) void gemm_kernel(const float* __restrict__ A,
                                                   const float* __restrict__ B,
                                                   float* __restrict__ C,
                                                   int M, int N, int K) {
    __shared__ float As[BK][BM];
    __shared__ float Bs[BK][BN + 4];

    int t = threadIdx.x;
    int m0 = blockIdx.x * BM;
    int n0 = blockIdx.y * BN;
    int tx = t & 15, ty = t >> 4;

    float acc[4][4] = {};

    int arow = t >> 2, ak = (t & 3) * 4;   // A tile load: 4 K-contig floats
    int bk = t >> 4, bn = (t & 15) * 4;    // B tile load: 4 N-contig floats

    for (int k0 = 0; k0 < K; k0 += BK) {
        {
            int gm = m0 + arow;
            float4 av = make_float4(0.f, 0.f, 0.f, 0.f);
            if (gm < M) av = *(const float4*)&A[gm * K + k0 + ak];
            As[ak + 0][arow] = av.x;
            As[ak + 1][arow] = av.y;
            As[ak + 2][arow] = av.z;
            As[ak + 3][arow] = av.w;
        }
        {
            int gn = n0 + bn;
            float4 bv = make_float4(0.f, 0.f, 0.f, 0.f);
            if (gn < N) bv = *(const float4*)&B[(k0 + bk) * N + gn];  // N%4==0 so full vec in-bounds
            *(float4*)&Bs[bk][bn] = bv;
        }
        __syncthreads();
#pragma unroll
        for (int k = 0; k < BK; ++k) {
            float4 a = *(const float4*)&As[k][ty * 4];
            float4 b = *(const float4*)&Bs[k][tx * 4];
            float av[4] = {a.x, a.y, a.z, a.w};
            float bv[4] = {b.x, b.y, b.z, b.w};
#pragma unroll
            for (int i = 0; i < 4; ++i)
#pragma unroll
                for (int j = 0; j < 4; ++j)
                    acc[i][j] += av[i] * bv[j];
        }
        __syncthreads();
    }

#pragma unroll
    for (int i = 0; i < 4; ++i) {
        int gm = m0 + ty * 4 + i;
        if (gm >= M) break;
#pragma unroll
        for (int j = 0; j < 4; ++j) {
            int gn = n0 + tx * 4 + j;
            if (gn < N) C[gm * N + gn] = acc[i][j];
        }
    }
}

// ---------------- spmm1: h1[row][o] += (1/cnt[col]) * hrel[col%N][(col/N)*16+o] ----------------
__global__ void spmm1_kernel(const int* __restrict__ rows, const int* __restrict__ cols,
                             const float* __restrict__ cnt, const float* __restrict__ hrel,
                             float* __restrict__ h1) {
    int tid = blockIdx.x * blockDim.x + threadIdx.x;
    int e = tid >> 4;
    if (e >= NE) return;
    int o = tid & 15;
    int col = cols[e];
    int row = rows[e];
    float v = 1.0f / cnt[col];
    int r = col / NN;
    int n = col - r * NN;
    float x = hrel[n * WJ + r * WS + o];
    atomicAdd(&h1[row * WS + o], v * x);
}

// ---------------- relu(h1 + bias1) in place ----------------
__global__ void relu_kernel(float* __restrict__ h1, const float* __restrict__ bias1) {
    int idx = blockIdx.x * blockDim.x + threadIdx.x;
    if (idx >= NN * WS) return;
    float v = h1[idx] + bias1[idx & 15];
    h1[idx] = v > 0.f ? v : 0.f;
}

// ---------------- w2[r][o][c] = sum_b comps2[r,b]*bases2[b,o,c] ----------------
__global__ void w2_kernel(const float* __restrict__ comps2, const float* __restrict__ bases2,
                          float* __restrict__ w2) {
    int idx = blockIdx.x * blockDim.x + threadIdx.x;   // r*800 + (o*50+c)
    if (idx >= RR * WS * NC) return;
    int r = idx / (WS * NC);
    int rem = idx - r * (WS * NC);
    float s = 0.f;
#pragma unroll
    for (int b = 0; b < NB; ++b)
        s += comps2[r * NB + b] * bases2[b * (WS * NC) + rem];
    w2[idx] = s;
}

// ---------------- out init: out[n][c] = bias2[c] ----------------
__global__ void initout_kernel(float* __restrict__ out, const float* __restrict__ bias2) {
    int idx = blockIdx.x * blockDim.x + threadIdx.x;
    if (idx >= NN * NC) return;
    out[idx] = bias2[idx % NC];
}

// ---------------- spmm2: wave per edge, lane = class ----------------
__global__ void spmm2_kernel(const int* __restrict__ rows, const int* __restrict__ cols,
                             const float* __restrict__ cnt, const float* __restrict__ h1,
                             const float* __restrict__ w2, float* __restrict__ out) {
    int tid = blockIdx.x * blockDim.x + threadIdx.x;
    int e = tid >> 6;
    int c = tid & 63;
    if (e >= NE || c >= NC) return;
    int col = cols[e];
    int row = rows[e];
    float v = 1.0f / cnt[col];
    int r = col / NN;
    int n = col - r * NN;
    const float* hp = &h1[n * WS];
    const float* wp = &w2[r * (WS * NC) + c];
    float s = 0.f;
#pragma unroll
    for (int o = 0; o < WS; ++o) s += hp[o] * wp[o * NC];
    atomicAdd(&out[row * NC + c], v * s);
}

extern "C" void kernel_launch(void* const* d_in, const int* in_sizes, int n_in,
                              void* d_out, int out_size, void* d_ws, size_t ws_size,
                              hipStream_t stream) {
    const float* X      = (const float*)d_in[0];   // (NN, ED)
    const float* comps1 = (const float*)d_in[1];   // (RR, NB)
    const float* bases1 = (const float*)d_in[2];   // (NB, ED, WS)
    const float* comps2 = (const float*)d_in[3];   // (RR, NB)
    const float* bases2 = (const float*)d_in[4];   // (NB, WS, NC)
    const float* bias1  = (const float*)d_in[5];   // (WS,)
    const float* bias2  = (const float*)d_in[6];   // (NC,)
    const int*   rows   = (const int*)d_in[7];     // (NE,)
    const int*   cols   = (const int*)d_in[8];     // (NE,)
    float* out = (float*)d_out;                    // (NN, NC)

    char* ws = (char*)d_ws;
    // workspace layout (256-aligned offsets), total ~168 MB
    float* cnt  = (float*)(ws + 0);           //  RR*NN      = 9,400,000 B
    float* Wbig = (float*)(ws + 9400064);     //  ED*WJ*4    = 4,812,800 B
    float* hrel = (float*)(ws + 14212864);    //  NN*WJ*4    = 150,400,000 B
    float* h1   = (float*)(ws + 164612864);   //  NN*WS*4    = 3,200,000 B
    float* w2   = (float*)(ws + 167812864);   //  RR*WS*NC*4 = 150,400 B

    hipMemsetAsync(cnt, 0, (size_t)RR * NN * 4, stream);
    hipMemsetAsync(h1, 0, (size_t)NN * WS * 4, stream);

    count_kernel<<<(NE + 255) / 256, 256, 0, stream>>>(cols, cnt);

    wbig_kernel<<<(ED * WJ + 255) / 256, 256, 0, stream>>>(comps1, bases1, Wbig);

    dim3 ggrid((NN + BM - 1) / BM, (WJ + BN - 1) / BN);
    gemm_kernel<<<ggrid, 256, 0, stream>>>(X, Wbig, hrel, NN, WJ, ED);

    spmm1_kernel<<<(NE * 16) / 256, 256, 0, stream>>>(rows, cols, cnt, hrel, h1);

    relu_kernel<<<(NN * WS + 255) / 256, 256, 0, stream>>>(h1, bias1);

    w2_kernel<<<(RR * WS * NC + 255) / 256, 256, 0, stream>>>(comps2, bases2, w2);

    initout_kernel<<<(NN * NC + 255) / 256, 256, 0, stream>>>(out, bias2);

    spmm2_kernel<<<(NE * 64) / 256, 256, 0, stream>>>(rows, cols, cnt, h1, w2, out);
}

// Round 2
// 1368.330 us; speedup vs baseline: 2.0421x; 2.0421x over previous
//
#include <hip/hip_runtime.h>
#include <hip/hip_bf16.h>

#define NN 50000      // nodes
#define RR 47         // relations
#define ED 1600       // emb dim (K)
#define WS 16         // weights size (layer1 out)
#define NC 50         // classes
#define NB 40         // bases
#define NE 1600000    // edges
#define WJ (RR*WS)    // 752 = layer1 fused output width
#define WJP 768       // WJ padded to 128 multiple

typedef unsigned short ushort_t;
typedef short s16x8 __attribute__((ext_vector_type(8)));
typedef float f32x4 __attribute__((ext_vector_type(4)));

__device__ __forceinline__ ushort_t f2bf(float f) {
    __hip_bfloat16 h = __float2bfloat16(f);
    ushort_t u;
    __builtin_memcpy(&u, &h, 2);
    return u;
}
__device__ __forceinline__ float bf2f(ushort_t u) {
    unsigned v = ((unsigned)u) << 16;
    float f;
    __builtin_memcpy(&f, &v, 4);
    return f;
}

__device__ __forceinline__ void async_copy16(const ushort_t* g, ushort_t* l) {
    __builtin_amdgcn_global_load_lds(
        (const __attribute__((address_space(1))) unsigned int*)g,
        (__attribute__((address_space(3))) unsigned int*)l,
        16, 0, 0);
}

// ---------------- cast X (fp32) -> bf16, 4 elems/thread ----------------
__global__ void cast_kernel(const float* __restrict__ X, ushort_t* __restrict__ A) {
    int idx = blockIdx.x * blockDim.x + threadIdx.x;   // float4 index
    if (idx >= (NN * ED) / 4) return;
    float4 v = ((const float4*)X)[idx];
    ushort_t* p = &A[idx * 4];
    p[0] = f2bf(v.x); p[1] = f2bf(v.y); p[2] = f2bf(v.z); p[3] = f2bf(v.w);
}

// ---------------- counting: cnt[col] += 1 ----------------
__global__ void count_kernel(const int* __restrict__ cols, float* __restrict__ cnt) {
    int e = blockIdx.x * blockDim.x + threadIdx.x;
    if (e < NE) atomicAdd(&cnt[cols[e]], 1.0f);
}

// ---------------- WbigB[j][i] = sum_b comps1[r,b]*bases1[b,i,o] (bf16, B^T, padded) ----------------
__global__ void wbigbt_kernel(const float* __restrict__ comps1, const float* __restrict__ bases1,
                              ushort_t* __restrict__ WbigB) {
    int idx = blockIdx.x * blockDim.x + threadIdx.x;   // j*ED + i
    if (idx >= WJP * ED) return;
    int j = idx / ED;
    int i = idx - j * ED;
    float s = 0.f;
    if (j < WJ) {
        int r = j >> 4;
        int o = j & 15;
#pragma unroll
        for (int b = 0; b < NB; ++b)
            s += comps1[r * NB + b] * bases1[(b * ED + i) * WS + o];
    }
    WbigB[idx] = f2bf(s);
}

// ---------------- MFMA bf16 GEMM: C[M,752] = A[M,1600] @ B^T, B:(768,1600) ----------------
// m97 structure: 128x128 tile, BK=32, 4 waves, 4x4 mfma_f32_16x16x32_bf16 per wave
__global__ __launch_bounds__(256) void mfma_gemm_kernel(const ushort_t* __restrict__ A,
                                                        const ushort_t* __restrict__ B,
                                                        ushort_t* __restrict__ C) {
    __shared__ ushort_t Abuf[128 * 32];   // 8 KB
    __shared__ ushort_t Bbuf[128 * 32];   // 8 KB

    const int t = threadIdx.x;
    const int lane = t & 63;
    const int wave = t >> 6;
    const int m0 = blockIdx.x * 128;
    const int n0 = blockIdx.y * 128;
    const int wm = (wave & 1) * 64;
    const int wn = (wave >> 1) * 64;

    // staging chunk geometry: 512 chunks of 16B per tile; thread t does chunks {t, t+256}
    const int arow0 = t >> 2,        akp0 = (t & 3) * 8;
    const int arow1 = (t + 256) >> 2, akp1 = ((t + 256) & 3) * 8;
    int gm0 = m0 + arow0; if (gm0 >= NN) gm0 = NN - 1;   // clamp: pad rows compute garbage, not stored
    int gm1 = m0 + arow1; if (gm1 >= NN) gm1 = NN - 1;
    const ushort_t* ap0 = &A[(size_t)gm0 * ED + akp0];
    const ushort_t* ap1 = &A[(size_t)gm1 * ED + akp1];
    const ushort_t* bp0 = &B[(size_t)(n0 + arow0) * ED + akp0];
    const ushort_t* bp1 = &B[(size_t)(n0 + arow1) * ED + akp1];

    f32x4 acc[4][4];
#pragma unroll
    for (int i = 0; i < 4; ++i)
#pragma unroll
        for (int j = 0; j < 4; ++j) acc[i][j] = (f32x4){0.f, 0.f, 0.f, 0.f};

    const int frow = lane & 15;       // m (or n) within 16-tile
    const int fk = (lane >> 4) * 8;   // k offset within 32

    for (int k0 = 0; k0 < ED; k0 += 32) {
        async_copy16(ap0 + k0, &Abuf[t * 8]);
        async_copy16(ap1 + k0, &Abuf[(t + 256) * 8]);
        async_copy16(bp0 + k0, &Bbuf[t * 8]);
        async_copy16(bp1 + k0, &Bbuf[(t + 256) * 8]);
        __syncthreads();

        s16x8 af[4], bf[4];
#pragma unroll
        for (int mt = 0; mt < 4; ++mt)
            af[mt] = *(const s16x8*)&Abuf[(wm + mt * 16 + frow) * 32 + fk];
#pragma unroll
        for (int nt = 0; nt < 4; ++nt)
            bf[nt] = *(const s16x8*)&Bbuf[(wn + nt * 16 + frow) * 32 + fk];
#pragma unroll
        for (int mt = 0; mt < 4; ++mt)
#pragma unroll
            for (int nt = 0; nt < 4; ++nt)
                acc[mt][nt] = __builtin_amdgcn_mfma_f32_16x16x32_bf16(af[mt], bf[nt], acc[mt][nt], 0, 0, 0);
        __syncthreads();
    }

    // C/D layout: col = lane&15, row = (lane>>4)*4 + reg
    const int cm = (lane >> 4) * 4;
    const int cn = lane & 15;
#pragma unroll
    for (int mt = 0; mt < 4; ++mt) {
#pragma unroll
        for (int i = 0; i < 4; ++i) {
            int gm = m0 + wm + mt * 16 + cm + i;
            if (gm >= NN) continue;
#pragma unroll
            for (int nt = 0; nt < 4; ++nt) {
                int gn = n0 + wn + nt * 16 + cn;
                if (gn < WJ) C[(size_t)gm * WJ + gn] = f2bf(acc[mt][nt][i]);
            }
        }
    }
}

// ---------------- spmm1: h1[row][o] += (1/cnt[col]) * hrel[col%N][(col/N)*16+o] ----------------
__global__ void spmm1_kernel(const int* __restrict__ rows, const int* __restrict__ cols,
                             const float* __restrict__ cnt, const ushort_t* __restrict__ hrel,
                             float* __restrict__ h1) {
    int tid = blockIdx.x * blockDim.x + threadIdx.x;
    int e = tid >> 4;
    if (e >= NE) return;
    int o = tid & 15;
    int col = cols[e];
    int row = rows[e];
    float v = 1.0f / cnt[col];
    int r = col / NN;
    int n = col - r * NN;
    float x = bf2f(hrel[(size_t)n * WJ + r * WS + o]);
    atomicAdd(&h1[row * WS + o], v * x);
}

// ---------------- relu(h1 + bias1) in place ----------------
__global__ void relu_kernel(float* __restrict__ h1, const float* __restrict__ bias1) {
    int idx = blockIdx.x * blockDim.x + threadIdx.x;
    if (idx >= NN * WS) return;
    float v = h1[idx] + bias1[idx & 15];
    h1[idx] = v > 0.f ? v : 0.f;
}

// ---------------- w2[r][o][c] = sum_b comps2[r,b]*bases2[b,o,c] ----------------
__global__ void w2_kernel(const float* __restrict__ comps2, const float* __restrict__ bases2,
                          float* __restrict__ w2) {
    int idx = blockIdx.x * blockDim.x + threadIdx.x;   // r*800 + (o*50+c)
    if (idx >= RR * WS * NC) return;
    int r = idx / (WS * NC);
    int rem = idx - r * (WS * NC);
    float s = 0.f;
#pragma unroll
    for (int b = 0; b < NB; ++b)
        s += comps2[r * NB + b] * bases2[b * (WS * NC) + rem];
    w2[idx] = s;
}

// ---------------- out init: out[n][c] = bias2[c] ----------------
__global__ void initout_kernel(float* __restrict__ out, const float* __restrict__ bias2) {
    int idx = blockIdx.x * blockDim.x + threadIdx.x;
    if (idx >= NN * NC) return;
    out[idx] = bias2[idx % NC];
}

// ---------------- spmm2: 64 threads per edge, lane = class ----------------
__global__ void spmm2_kernel(const int* __restrict__ rows, const int* __restrict__ cols,
                             const float* __restrict__ cnt, const float* __restrict__ h1,
                             const float* __restrict__ w2, float* __restrict__ out) {
    int tid = blockIdx.x * blockDim.x + threadIdx.x;
    int e = tid >> 6;
    int c = tid & 63;
    if (e >= NE || c >= NC) return;
    int col = cols[e];
    int row = rows[e];
    float v = 1.0f / cnt[col];
    int r = col / NN;
    int n = col - r * NN;
    const float* hp = &h1[n * WS];
    const float* wp = &w2[r * (WS * NC) + c];
    float s = 0.f;
#pragma unroll
    for (int o = 0; o < WS; ++o) s += hp[o] * wp[o * NC];
    atomicAdd(&out[row * NC + c], v * s);
}

extern "C" void kernel_launch(void* const* d_in, const int* in_sizes, int n_in,
                              void* d_out, int out_size, void* d_ws, size_t ws_size,
                              hipStream_t stream) {
    const float* X      = (const float*)d_in[0];   // (NN, ED)
    const float* comps1 = (const float*)d_in[1];   // (RR, NB)
    const float* bases1 = (const float*)d_in[2];   // (NB, ED, WS)
    const float* comps2 = (const float*)d_in[3];   // (RR, NB)
    const float* bases2 = (const float*)d_in[4];   // (NB, WS, NC)
    const float* bias1  = (const float*)d_in[5];   // (WS,)
    const float* bias2  = (const float*)d_in[6];   // (NC,)
    const int*   rows   = (const int*)d_in[7];     // (NE,)
    const int*   cols   = (const int*)d_in[8];     // (NE,)
    float* out = (float*)d_out;                    // (NN, NC)

    char* ws = (char*)d_ws;
    // workspace layout (256-aligned), total ~250 MB
    float*    cnt   = (float*)   (ws + 0);           // RR*NN*4      =   9,400,000 B
    ushort_t* Abf   = (ushort_t*)(ws + 9400064);     // NN*ED*2      = 160,000,000 B
    ushort_t* WbigB = (ushort_t*)(ws + 169400064);   // WJP*ED*2     =   2,457,600 B
    ushort_t* hrel  = (ushort_t*)(ws + 171857664);   // NN*WJ*2      =  75,200,000 B
    float*    h1    = (float*)   (ws + 247057664);   // NN*WS*4      =   3,200,000 B
    float*    w2    = (float*)   (ws + 250257664);   // RR*WS*NC*4   =     150,400 B

    hipMemsetAsync(cnt, 0, (size_t)RR * NN * 4, stream);
    hipMemsetAsync(h1, 0, (size_t)NN * WS * 4, stream);

    cast_kernel<<<(NN * ED / 4 + 255) / 256, 256, 0, stream>>>(X, Abf);
    count_kernel<<<(NE + 255) / 256, 256, 0, stream>>>(cols, cnt);
    wbigbt_kernel<<<(WJP * ED + 255) / 256, 256, 0, stream>>>(comps1, bases1, WbigB);

    dim3 ggrid((NN + 127) / 128, WJP / 128);
    mfma_gemm_kernel<<<ggrid, 256, 0, stream>>>(Abf, WbigB, hrel);

    spmm1_kernel<<<(NE * 16) / 256, 256, 0, stream>>>(rows, cols, cnt, hrel, h1);
    relu_kernel<<<(NN * WS + 255) / 256, 256, 0, stream>>>(h1, bias1);
    w2_kernel<<<(RR * WS * NC + 255) / 256, 256, 0, stream>>>(comps2, bases2, w2);
    initout_kernel<<<(NN * NC + 255) / 256, 256, 0, stream>>>(out, bias2);
    spmm2_kernel<<<(NE * 64) / 256, 256, 0, stream>>>(rows, cols, cnt, h1, w2, out);
}

// Round 3
// 1101.622 us; speedup vs baseline: 2.5365x; 1.2421x over previous
//
#include <hip/hip_runtime.h>
#include <hip/hip_bf16.h>

#define NN 50000      // nodes
#define RR 47         // relations
#define ED 1600       // emb dim (K)
#define WS 16         // weights size (layer1 out)
#define NC 50         // classes
#define NB 40         // bases
#define NE 1600000    // edges
#define WJ (RR*WS)    // 752 = layer1 fused output width
#define WJP 768       // WJ padded to 128 multiple

typedef unsigned short ushort_t;
typedef short s16x8 __attribute__((ext_vector_type(8)));
typedef float f32x4 __attribute__((ext_vector_type(4)));

__device__ __forceinline__ ushort_t f2bf(float f) {
    __hip_bfloat16 h = __float2bfloat16(f);
    ushort_t u;
    __builtin_memcpy(&u, &h, 2);
    return u;
}
__device__ __forceinline__ float bf2f(ushort_t u) {
    unsigned v = ((unsigned)u) << 16;
    float f;
    __builtin_memcpy(&f, &v, 4);
    return f;
}

__device__ __forceinline__ void async_copy16(const ushort_t* g, ushort_t* l) {
    __builtin_amdgcn_global_load_lds(
        (const __attribute__((address_space(1))) unsigned int*)g,
        (__attribute__((address_space(3))) unsigned int*)l,
        16, 0, 0);
}

// ---------------- cast X (fp32) -> bf16, 4 elems/thread ----------------
__global__ void cast_kernel(const float* __restrict__ X, ushort_t* __restrict__ A) {
    int idx = blockIdx.x * blockDim.x + threadIdx.x;   // float4 index
    if (idx >= (NN * ED) / 4) return;
    float4 v = ((const float4*)X)[idx];
    ushort_t* p = &A[idx * 4];
    p[0] = f2bf(v.x); p[1] = f2bf(v.y); p[2] = f2bf(v.z); p[3] = f2bf(v.w);
}

// ---------------- counting: cnt[col] += 1 ----------------
__global__ void count_kernel(const int* __restrict__ cols, float* __restrict__ cnt) {
    int e = blockIdx.x * blockDim.x + threadIdx.x;
    if (e < NE) atomicAdd(&cnt[cols[e]], 1.0f);
}

// ---------------- WbigB[j][i] = sum_b comps1[r,b]*bases1[b,i,o] (bf16, B^T, padded) ----------------
__global__ void wbigbt_kernel(const float* __restrict__ comps1, const float* __restrict__ bases1,
                              ushort_t* __restrict__ WbigB) {
    int idx = blockIdx.x * blockDim.x + threadIdx.x;   // j*ED + i
    if (idx >= WJP * ED) return;
    int j = idx / ED;
    int i = idx - j * ED;
    float s = 0.f;
    if (j < WJ) {
        int r = j >> 4;
        int o = j & 15;
#pragma unroll
        for (int b = 0; b < NB; ++b)
            s += comps1[r * NB + b] * bases1[(b * ED + i) * WS + o];
    }
    WbigB[idx] = f2bf(s);
}

// ---------------- MFMA bf16 GEMM: C[M,752] = A[M,1600] @ B^T, B:(768,1600) ----------------
__global__ __launch_bounds__(256) void mfma_gemm_kernel(const ushort_t* __restrict__ A,
                                                        const ushort_t* __restrict__ B,
                                                        ushort_t* __restrict__ C) {
    __shared__ ushort_t Abuf[128 * 32];   // 8 KB
    __shared__ ushort_t Bbuf[128 * 32];   // 8 KB

    const int t = threadIdx.x;
    const int lane = t & 63;
    const int wave = t >> 6;
    const int m0 = blockIdx.x * 128;
    const int n0 = blockIdx.y * 128;
    const int wm = (wave & 1) * 64;
    const int wn = (wave >> 1) * 64;

    const int arow0 = t >> 2,        akp0 = (t & 3) * 8;
    const int arow1 = (t + 256) >> 2, akp1 = ((t + 256) & 3) * 8;
    int gm0 = m0 + arow0; if (gm0 >= NN) gm0 = NN - 1;
    int gm1 = m0 + arow1; if (gm1 >= NN) gm1 = NN - 1;
    const ushort_t* ap0 = &A[(size_t)gm0 * ED + akp0];
    const ushort_t* ap1 = &A[(size_t)gm1 * ED + akp1];
    const ushort_t* bp0 = &B[(size_t)(n0 + arow0) * ED + akp0];
    const ushort_t* bp1 = &B[(size_t)(n0 + arow1) * ED + akp1];

    f32x4 acc[4][4];
#pragma unroll
    for (int i = 0; i < 4; ++i)
#pragma unroll
        for (int j = 0; j < 4; ++j) acc[i][j] = (f32x4){0.f, 0.f, 0.f, 0.f};

    const int frow = lane & 15;
    const int fk = (lane >> 4) * 8;

    for (int k0 = 0; k0 < ED; k0 += 32) {
        async_copy16(ap0 + k0, &Abuf[t * 8]);
        async_copy16(ap1 + k0, &Abuf[(t + 256) * 8]);
        async_copy16(bp0 + k0, &Bbuf[t * 8]);
        async_copy16(bp1 + k0, &Bbuf[(t + 256) * 8]);
        __syncthreads();

        s16x8 af[4], bf[4];
#pragma unroll
        for (int mt = 0; mt < 4; ++mt)
            af[mt] = *(const s16x8*)&Abuf[(wm + mt * 16 + frow) * 32 + fk];
#pragma unroll
        for (int nt = 0; nt < 4; ++nt)
            bf[nt] = *(const s16x8*)&Bbuf[(wn + nt * 16 + frow) * 32 + fk];
#pragma unroll
        for (int mt = 0; mt < 4; ++mt)
#pragma unroll
            for (int nt = 0; nt < 4; ++nt)
                acc[mt][nt] = __builtin_amdgcn_mfma_f32_16x16x32_bf16(af[mt], bf[nt], acc[mt][nt], 0, 0, 0);
        __syncthreads();
    }

    const int cm = (lane >> 4) * 4;
    const int cn = lane & 15;
#pragma unroll
    for (int mt = 0; mt < 4; ++mt) {
#pragma unroll
        for (int i = 0; i < 4; ++i) {
            int gm = m0 + wm + mt * 16 + cm + i;
            if (gm >= NN) continue;
#pragma unroll
            for (int nt = 0; nt < 4; ++nt) {
                int gn = n0 + wn + nt * 16 + cn;
                if (gn < WJ) C[(size_t)gm * WJ + gn] = f2bf(acc[mt][nt][i]);
            }
        }
    }
}

// ---------------- spmm1: h1[row][o] += (1/cnt[col]) * hrel[col%N][(col/N)*16+o] ----------------
__global__ void spmm1_kernel(const int* __restrict__ rows, const int* __restrict__ cols,
                             const float* __restrict__ cnt, const ushort_t* __restrict__ hrel,
                             float* __restrict__ h1) {
    int tid = blockIdx.x * blockDim.x + threadIdx.x;
    int e = tid >> 4;
    if (e >= NE) return;
    int o = tid & 15;
    int col = cols[e];
    int row = rows[e];
    float v = 1.0f / cnt[col];
    int r = col / NN;
    int n = col - r * NN;
    float x = bf2f(hrel[(size_t)n * WJ + r * WS + o]);
    atomicAdd(&h1[row * WS + o], v * x);
}

// ---------------- relu(h1 + bias1) in place ----------------
__global__ void relu_kernel(float* __restrict__ h1, const float* __restrict__ bias1) {
    int idx = blockIdx.x * blockDim.x + threadIdx.x;
    if (idx >= NN * WS) return;
    float v = h1[idx] + bias1[idx & 15];
    h1[idx] = v > 0.f ? v : 0.f;
}

// ---------------- w2p[k][c] (k=r*16+o, c padded to 64) = sum_b comps2[r,b]*bases2[b,o,c] ----------------
__global__ void w2p_kernel(const float* __restrict__ comps2, const float* __restrict__ bases2,
                           float* __restrict__ w2p) {
    int idx = blockIdx.x * blockDim.x + threadIdx.x;   // k*64 + c
    if (idx >= WJ * 64) return;
    int k = idx >> 6;
    int c = idx & 63;
    float s = 0.f;
    if (c < NC) {
        int r = k >> 4;
        int o = k & 15;
#pragma unroll
        for (int b = 0; b < NB; ++b)
            s += comps2[r * NB + b] * bases2[(b * WS + o) * NC + c];
    }
    w2p[idx] = s;
}

// ---------------- agg: G[row][r*16+o] += (1/cnt[col]) * h1[col%N][o] ----------------
__global__ void agg_kernel(const int* __restrict__ rows, const int* __restrict__ cols,
                           const float* __restrict__ cnt, const float* __restrict__ h1,
                           float* __restrict__ G) {
    int tid = blockIdx.x * blockDim.x + threadIdx.x;
    int e = tid >> 4;
    if (e >= NE) return;
    int o = tid & 15;
    int col = cols[e];
    int row = rows[e];
    float v = 1.0f / cnt[col];
    int r = col / NN;
    int n = col - r * NN;
    float x = h1[n * WS + o];
    atomicAdd(&G[(size_t)row * WJ + r * WS + o], v * x);
}

// ---------------- gemm2: out[m][c] = bias2[c] + sum_k G[m][k] * w2p[k][c] ----------------
__global__ __launch_bounds__(256) void gemm2_kernel(const float* __restrict__ G,
                                                    const float* __restrict__ w2p,
                                                    const float* __restrict__ bias2,
                                                    float* __restrict__ out) {
    __shared__ float As[16][64];
    __shared__ float Bs[16][64 + 4];

    int t = threadIdx.x;
    int m0 = blockIdx.x * 64;
    int tx = t & 15, ty = t >> 4;

    float acc[4][4] = {};

    int arow = t >> 2, ak = (t & 3) * 4;
    int bk = t >> 4, bn = (t & 15) * 4;

    for (int k0 = 0; k0 < WJ; k0 += 16) {
        {
            int gm = m0 + arow;
            float4 av = make_float4(0.f, 0.f, 0.f, 0.f);
            if (gm < NN) av = *(const float4*)&G[(size_t)gm * WJ + k0 + ak];
            As[ak + 0][arow] = av.x;
            As[ak + 1][arow] = av.y;
            As[ak + 2][arow] = av.z;
            As[ak + 3][arow] = av.w;
        }
        {
            float4 bv = *(const float4*)&w2p[(k0 + bk) * 64 + bn];
            *(float4*)&Bs[bk][bn] = bv;
        }
        __syncthreads();
#pragma unroll
        for (int k = 0; k < 16; ++k) {
            float4 a = *(const float4*)&As[k][ty * 4];
            float4 b = *(const float4*)&Bs[k][tx * 4];
            float av[4] = {a.x, a.y, a.z, a.w};
            float bv[4] = {b.x, b.y, b.z, b.w};
#pragma unroll
            for (int i = 0; i < 4; ++i)
#pragma unroll
                for (int j = 0; j < 4; ++j)
                    acc[i][j] += av[i] * bv[j];
        }
        __syncthreads();
    }

#pragma unroll
    for (int i = 0; i < 4; ++i) {
        int gm = m0 + ty * 4 + i;
        if (gm >= NN) break;
#pragma unroll
        for (int j = 0; j < 4; ++j) {
            int gn = tx * 4 + j;
            if (gn < NC) out[gm * NC + gn] = acc[i][j] + bias2[gn];
        }
    }
}

extern "C" void kernel_launch(void* const* d_in, const int* in_sizes, int n_in,
                              void* d_out, int out_size, void* d_ws, size_t ws_size,
                              hipStream_t stream) {
    const float* X      = (const float*)d_in[0];   // (NN, ED)
    const float* comps1 = (const float*)d_in[1];   // (RR, NB)
    const float* bases1 = (const float*)d_in[2];   // (NB, ED, WS)
    const float* comps2 = (const float*)d_in[3];   // (RR, NB)
    const float* bases2 = (const float*)d_in[4];   // (NB, WS, NC)
    const float* bias1  = (const float*)d_in[5];   // (WS,)
    const float* bias2  = (const float*)d_in[6];   // (NC,)
    const int*   rows   = (const int*)d_in[7];     // (NE,)
    const int*   cols   = (const int*)d_in[8];     // (NE,)
    float* out = (float*)d_out;                    // (NN, NC)

    char* ws = (char*)d_ws;
    // workspace layout (64-aligned), ~250.5 MB. G aliases Abf (dead after mfma_gemm).
    float*    cnt   = (float*)   (ws + 0);           // RR*NN*4    =   9,400,000 B
    ushort_t* Abf   = (ushort_t*)(ws + 9400064);     // NN*ED*2    = 160,000,000 B
    float*    G     = (float*)   (ws + 9400064);     // NN*WJ*4    = 150,400,000 B (alias)
    ushort_t* WbigB = (ushort_t*)(ws + 169400064);   // WJP*ED*2   =   2,457,600 B
    ushort_t* hrel  = (ushort_t*)(ws + 171857664);   // NN*WJ*2    =  75,200,000 B
    float*    h1    = (float*)   (ws + 247057664);   // NN*WS*4    =   3,200,000 B
    float*    w2p   = (float*)   (ws + 250257664);   // WJ*64*4    =     192,512 B

    hipMemsetAsync(cnt, 0, (size_t)RR * NN * 4, stream);
    hipMemsetAsync(h1, 0, (size_t)NN * WS * 4, stream);

    cast_kernel<<<(NN * ED / 4 + 255) / 256, 256, 0, stream>>>(X, Abf);
    count_kernel<<<(NE + 255) / 256, 256, 0, stream>>>(cols, cnt);
    wbigbt_kernel<<<(WJP * ED + 255) / 256, 256, 0, stream>>>(comps1, bases1, WbigB);

    dim3 ggrid((NN + 127) / 128, WJP / 128);
    mfma_gemm_kernel<<<ggrid, 256, 0, stream>>>(Abf, WbigB, hrel);

    spmm1_kernel<<<(NE * 16) / 256, 256, 0, stream>>>(rows, cols, cnt, hrel, h1);
    relu_kernel<<<(NN * WS + 255) / 256, 256, 0, stream>>>(h1, bias1);
    w2p_kernel<<<(WJ * 64 + 255) / 256, 256, 0, stream>>>(comps2, bases2, w2p);

    // G aliases Abf: safe because stream order puts this after mfma_gemm consumed Abf
    hipMemsetAsync(G, 0, (size_t)NN * WJ * 4, stream);
    agg_kernel<<<(NE * 16) / 256, 256, 0, stream>>>(rows, cols, cnt, h1, G);

    gemm2_kernel<<<(NN + 63) / 64, 256, 0, stream>>>(G, w2p, bias2, out);
}